// Round 6
// baseline (419.525 us; speedup 1.0000x reference)
//
#include <hip/hip_runtime.h>
#include <hip/hip_bf16.h>
#include <stdint.h>

#define BATCH 8192
#define DIM   2048
#define NEXP  8
#define BM    128
#define BN    128
#define BK    32
#define NITER (DIM / BK)   // 64
#define MAX_TILES 72
#define NBLK  (DIM / BN)   // 16
#define NROWS 9216         // BATCH + max padding (8*128)
#define XROWB 2304         // x gather blocks: 9216 rows / 4 rows per block

typedef __bf16 bf16x8 __attribute__((ext_vector_type(8)));
typedef float  f32x4  __attribute__((ext_vector_type(4)));

// ---- workspace layout ----
// metadata ints 0..511 (ntiles@48 tileExp@64 tilePos0@160 tileVal@256)
// rowmap @ int 512 (9216 ints, ends byte 38912)
// xg (bf16, compacted+padded rows) @ byte 40960 (37.75 MB) -- no Wb anymore
#define XG_BYTE_OFF 40960ull
#define WS_NEED     37789696ull

#define AS1(p) ((const __attribute__((address_space(1))) void*)(p))
#define AS3(p) ((__attribute__((address_space(3))) void*)(p))

__device__ __forceinline__ unsigned f2bf2(float lo, float hi) {
    unsigned ul = __float_as_uint(lo), uh = __float_as_uint(hi);
    ul = (ul + 0x7FFFu + ((ul >> 16) & 1u)) >> 16;   // RNE
    uh = (uh + 0x7FFFu + ((uh >> 16) & 1u)) >> 16;
    return (uh << 16) | ul;
}

// single block: histogram -> per-expert wave-parallel scan (8 waves == NEXP)
// -> tile table -> rowmap (compacted position -> original row; -1 = padding).
// No atomics.
__global__ __launch_bounds__(512)
void k_plan(const int* __restrict__ ids, int* __restrict__ ws,
            int* __restrict__ rowmap) {
    __shared__ int sc[512 * NEXP];   // per-thread per-expert counts -> prefixes
    __shared__ int seg[NEXP];
    __shared__ int tot[NEXP];
    int t = threadIdx.x;
    int myids[16];
    int base = t * 16;               // each thread owns 16 consecutive rows
#pragma unroll
    for (int e = 0; e < NEXP; e++) sc[t * NEXP + e] = 0;
#pragma unroll
    for (int i = 0; i < 16; i++) {
        myids[i] = ids[base + i];
        sc[t * NEXP + myids[i]]++;
    }
    __syncthreads();
    // wave w computes exclusive prefix over the 512 counts of expert w
    {
        int w = t >> 6, l = t & 63;
        int e = w;
        int vals[8], sum = 0;
#pragma unroll
        for (int j = 0; j < 8; j++) { vals[j] = sc[(l * 8 + j) * NEXP + e]; sum += vals[j]; }
        int inc = sum;
        for (int d = 1; d < 64; d <<= 1) {
            int v = __shfl_up(inc, d, 64);
            if (l >= d) inc += v;
        }
        int run = inc - sum;         // exclusive
#pragma unroll
        for (int j = 0; j < 8; j++) { int v = vals[j]; sc[(l * 8 + j) * NEXP + e] = run; run += v; }
        if (l == 63) tot[e] = run;
    }
    __syncthreads();
    if (t == 0) {
        int pos = 0, mt = 0;
        for (int e = 0; e < NEXP; e++) {
            int c = tot[e];
            seg[e] = pos;
            int ntl = (c + BM - 1) / BM;
            for (int tt = 0; tt < ntl; tt++) {
                ws[64  + mt] = e;
                ws[160 + mt] = pos + tt * BM;
                int v = c - tt * BM;
                ws[256 + mt] = v < BM ? v : BM;
                mt++;
            }
            pos += ntl * BM;
        }
        ws[48] = mt;
    }
    __syncthreads();
    for (int i = t; i < NROWS; i += 512) rowmap[i] = -1;
    __syncthreads();                 // init drained before fills
#pragma unroll
    for (int i = 0; i < 16; i++) {
        int e = myids[i];
        int p = seg[e] + sc[t * NEXP + e]++;
        rowmap[p] = base + i;
    }
}

// prep is now ONLY the x gather+convert (102 MB total traffic):
//   block b converts 4 compacted rows: xg[row] = bf16(x[rowmap[row]])
//   (zeros if padding); 16B-in / 8B-out per thread per row, coalesced.
__global__ __launch_bounds__(512)
void k_prep(const float* __restrict__ x, const int* __restrict__ rowmap,
            unsigned short* __restrict__ xg) {
    int b = blockIdx.x;
    int t = threadIdx.x;
    int rm[4];
#pragma unroll
    for (int r = 0; r < 4; r++) rm[r] = rowmap[b * 4 + r];
#pragma unroll
    for (int r = 0; r < 4; r++) {
        int row = b * 4 + r;
        uint2* o = (uint2*)(xg + (size_t)row * DIM);
        if (rm[r] < 0) { o[t] = make_uint2(0, 0); continue; }
        float4 a = ((const float4*)(x + (size_t)rm[r] * DIM))[t];
        uint2 v;
        v.x = f2bf2(a.x, a.y);
        v.y = f2bf2(a.z, a.w);
        o[t] = v;
    }
}

// grouped GEMM: 128x128 tile, 4 waves (2x2 of 64x64), BK=32, double-buffered
// LDS, proven single-barrier schedule (prefetch i+1 during compute i;
// __syncthreads drains vmcnt(0)).
// A: bf16 from xg (compacted), global_load_lds, 2-way-aliased chunk swizzle
//    (16B chunk at pos p of row r holds logical p ^ ((r>>1)&3)).
// B: **fp32 directly from W** (no conversion pass!), global_load_lds,
//    16 KB/iter; row = 32 fp32 = 8 chunks of 16B; physical chunk p of row r
//    holds logical p ^ (r&7) (source pre-swizzle) -> reader's two
//    ds_read_b128 spread across 8 bank-groups (2-way = free).
//    fp32->bf16 conversion happens at the LDS->reg fragment read (lgkmcnt
//    dependency, post-barrier -- nothing for the compiler to hoist; this
//    avoids round-3's vmcnt-hoist pathology).
// Grid dim3(16,72): XCD = nb%8 (proven mapping).
__launch_bounds__(256)
__global__ void k_gemm(const unsigned short* __restrict__ xg,
                       const float* __restrict__ W,
                       const float* __restrict__ bias,
                       const int* __restrict__ ws, const int* __restrict__ rowmap,
                       float* __restrict__ out) {
    int mt = blockIdx.y;
    if (mt >= ws[48]) return;
    int e     = ws[64  + mt];
    int pos0  = ws[160 + mt];
    int valid = ws[256 + mt];
    int n0 = blockIdx.x * BN;

    // [buf]: bytes 0..8191 = A (bf16 128x32), 8192..24575 = B (fp32 128x32)
    __shared__ unsigned char lds[2][24576];   // 48 KB -> 3 blocks/CU

    int tid = threadIdx.x;
    int w = tid >> 6, l = tid & 63;
    int lane15 = l & 15, quad = l >> 4;
    int wave_m = (w >> 1) * 64, wave_n = (w & 1) * 64;

    const unsigned short* Abase = xg + (size_t)pos0 * DIM;
    const float* Bbase = W + ((size_t)e * DIM + n0) * DIM;

    // ---- A staging source offsets (shorts); 512 chunks of 16B, wave w
    // stages chunks [w*128, w*128+128) in 2 issues of 64.
    // chunk c: row=c>>2, pos=c&3, src q = pos^((row>>1)&3)
    int srcA[2];
#pragma unroll
    for (int j = 0; j < 2; j++) {
        int c = w * 128 + j * 64 + l;
        int row = c >> 2, pos = c & 3;
        int q = pos ^ ((row >> 1) & 3);
        srcA[j] = row * DIM + q * 8;
    }
    // ---- B staging source offsets (floats); 1024 chunks of 16B, wave w
    // stages chunks [w*256, w*256+256) in 4 issues of 64.
    // chunk c: row=c>>3, pos=c&7, src q = pos^(row&7)
    int srcB[4];
#pragma unroll
    for (int j = 0; j < 4; j++) {
        int c = w * 256 + j * 64 + l;
        int row = c >> 3, pos = c & 7;
        int q = pos ^ (row & 7);
        srcB[j] = row * DIM + q * 4;
    }

    // ---- fragment read offsets (bytes), loop-invariant ----
    // A: reader wants logical k-chunk = quad of row r; physical = quad^((r>>1)&3),
    //    and (r>>1)&3 == (lane15>>1)&3 for the rows this lane touches.
    int aswz = (quad ^ ((lane15 >> 1) & 3)) * 16;
    int afOff[4];
#pragma unroll
    for (int mi = 0; mi < 4; mi++)
        afOff[mi] = (wave_m + mi * 16 + lane15) * (BK * 2) + aswz;
    // B: row r, logical fp32 chunks {quad*2, quad*2+1}; physical = logical^(r&7)
    int b0Off[4], b1Off[4];
#pragma unroll
    for (int ni = 0; ni < 4; ni++) {
        int r = wave_n + ni * 16 + lane15;
        int s = r & 7;
        b0Off[ni] = 8192 + r * 128 + ((quad * 2)     ^ s) * 16;
        b1Off[ni] = 8192 + r * 128 + ((quad * 2 + 1) ^ s) * 16;
    }

    f32x4 acc[4][4];
#pragma unroll
    for (int i = 0; i < 4; i++)
#pragma unroll
        for (int j = 0; j < 4; j++) acc[i][j] = (f32x4){0.f, 0.f, 0.f, 0.f};

#define ISSUE(buf, k0)                                                         \
    do {                                                                       \
        _Pragma("unroll")                                                      \
        for (int j = 0; j < 2; j++)                                            \
            __builtin_amdgcn_global_load_lds(                                  \
                AS1(Abase + (k0) + srcA[j]),                                   \
                AS3(&lds[buf][w * 2048 + j * 1024]), 16, 0, 0);                \
        _Pragma("unroll")                                                      \
        for (int j = 0; j < 4; j++)                                            \
            __builtin_amdgcn_global_load_lds(                                  \
                AS1(Bbase + (k0) + srcB[j]),                                   \
                AS3(&lds[buf][8192 + w * 4096 + j * 1024]), 16, 0, 0);         \
    } while (0)

    ISSUE(0, 0);
    int cur = 0;
    for (int i = 0; i < NITER; ++i) {
        __syncthreads();   // drains vmcnt(0): loads(i) landed; compute(i-1) done
        if (i + 1 < NITER) {
            int k0n = (i + 1) * BK;
            ISSUE(cur ^ 1, k0n);
        }
        bf16x8 af[4], bf[4];
#pragma unroll
        for (int mi = 0; mi < 4; mi++)
            af[mi] = *(const bf16x8*)(&lds[cur][afOff[mi]]);
#pragma unroll
        for (int ni = 0; ni < 4; ni++) {
            float4 u = *(const float4*)(&lds[cur][b0Off[ni]]);
            float4 v = *(const float4*)(&lds[cur][b1Off[ni]]);
            bf16x8 tbf;
            tbf[0] = (__bf16)u.x; tbf[1] = (__bf16)u.y;
            tbf[2] = (__bf16)u.z; tbf[3] = (__bf16)u.w;
            tbf[4] = (__bf16)v.x; tbf[5] = (__bf16)v.y;
            tbf[6] = (__bf16)v.z; tbf[7] = (__bf16)v.w;
            bf[ni] = tbf;
        }
#pragma unroll
        for (int mi = 0; mi < 4; mi++)
#pragma unroll
            for (int ni = 0; ni < 4; ni++)
                acc[mi][ni] = __builtin_amdgcn_mfma_f32_16x16x32_bf16(
                    af[mi], bf[ni], acc[mi][ni], 0, 0, 0);
        cur ^= 1;
    }
#undef ISSUE

    // epilogue: bias + relu + residual(from xg, bf16, contiguous) + scatter
    float bv[4];
#pragma unroll
    for (int ni = 0; ni < 4; ni++)
        bv[ni] = bias[(size_t)e * DIM + n0 + wave_n + ni * 16 + lane15];
#pragma unroll
    for (int mi = 0; mi < 4; mi++) {
#pragma unroll
        for (int r4 = 0; r4 < 4; r4++) {
            int rl = wave_m + mi * 16 + quad * 4 + r4;
            if (rl < valid) {
                int orig = rowmap[pos0 + rl];
                const unsigned short* xrow = xg + (size_t)(pos0 + rl) * DIM + n0;
                float* orow = out + (size_t)orig * DIM + n0;
#pragma unroll
                for (int ni = 0; ni < 4; ni++) {
                    int col = wave_n + ni * 16 + lane15;
                    float xv = __uint_as_float((unsigned)xrow[col] << 16);
                    float v = acc[mi][ni][r4] + bv[ni];
                    v = v > 0.f ? v : 0.f;
                    orow[col] = xv + v;
                }
            }
        }
    }
}

// slow-but-correct fallback if workspace is too small
__global__ void k_naive(const float* __restrict__ x, const int* __restrict__ ids,
                        const float* __restrict__ W, const float* __restrict__ b,
                        float* __restrict__ out) {
    __shared__ float lx[DIM];
    int i = blockIdx.x;
    for (int t = threadIdx.x; t < DIM; t += blockDim.x) lx[t] = x[(size_t)i * DIM + t];
    __syncthreads();
    int e = ids[i];
    const float* We = W + (size_t)e * DIM * DIM;
    for (int n = threadIdx.x; n < DIM; n += blockDim.x) {
        const float* wr = We + (size_t)n * DIM;
        float acc = 0.f;
        for (int k = 0; k < DIM; k += 4) {
            float4 w4 = *(const float4*)(wr + k);
            acc += lx[k] * w4.x + lx[k + 1] * w4.y + lx[k + 2] * w4.z + lx[k + 3] * w4.w;
        }
        float v = acc + b[(size_t)e * DIM + n];
        v = v > 0.f ? v : 0.f;
        out[(size_t)i * DIM + n] = lx[n] + v;
    }
}

extern "C" void kernel_launch(void* const* d_in, const int* in_sizes, int n_in,
                              void* d_out, int out_size, void* d_ws, size_t ws_size,
                              hipStream_t stream) {
    const float* x   = (const float*)d_in[0];
    const int*   ids = (const int*)d_in[1];
    const float* W   = (const float*)d_in[2];
    const float* b   = (const float*)d_in[3];
    float* out = (float*)d_out;

    if (ws_size < WS_NEED) {
        k_naive<<<BATCH, 256, 0, stream>>>(x, ids, W, b, out);
        return;
    }

    char* wsb = (char*)d_ws;
    int*  wsi = (int*)wsb;
    int* rowmap = wsi + 512;
    unsigned short* xg = (unsigned short*)(wsb + XG_BYTE_OFF);

    k_plan<<<1, 512, 0, stream>>>(ids, wsi, rowmap);
    k_prep<<<XROWB, 512, 0, stream>>>(x, rowmap, xg);
    dim3 g(NBLK, MAX_TILES);
    k_gemm<<<g, 256, 0, stream>>>(xg, W, b, wsi, rowmap, out);
}

// Round 7
// 395.529 us; speedup vs baseline: 1.0607x; 1.0607x over previous
//
#include <hip/hip_runtime.h>
#include <hip/hip_bf16.h>
#include <stdint.h>

#define BATCH 8192
#define DIM   2048
#define NEXP  8
#define BM    128
#define BN    128
#define BK    32
#define NITER (DIM / BK)   // 64
#define MAX_TILES 72
#define NBLK  (DIM / BN)   // 16
#define NROWS 9216         // BATCH + max padding (8*128)
#define XHALF 4608         // x gather blocks: 9216 rows / 2 rows per block
#define WCVTB 4096         // W cvt blocks: 4.19M uint4-chunks / (256thr*4)

typedef __bf16 bf16x8 __attribute__((ext_vector_type(8)));
typedef float  f32x4  __attribute__((ext_vector_type(4)));

// ---- workspace layout ----
// metadata ints 0..511 (ntiles@48 tileExp@64 tilePos0@160 tileVal@256)
// rowmap @ int 512 (9216 ints, ends byte 38912)
// xg (bf16, compacted+padded rows) @ byte 40960 (37.75 MB)
// Wb (bf16) @ byte 37,789,696 (67 MB, ends exactly at WS_NEED)
#define XG_BYTE_OFF 40960ull
#define WB_BYTE_OFF 37789696ull
#define WS_NEED     104898560ull

#define AS1(p) ((const __attribute__((address_space(1))) void*)(p))
#define AS3(p) ((__attribute__((address_space(3))) void*)(p))

__device__ __forceinline__ unsigned f2bf2(float lo, float hi) {
    unsigned ul = __float_as_uint(lo), uh = __float_as_uint(hi);
    ul = (ul + 0x7FFFu + ((ul >> 16) & 1u)) >> 16;   // RNE
    uh = (uh + 0x7FFFu + ((uh >> 16) & 1u)) >> 16;
    return (uh << 16) | ul;
}

// single block: histogram -> per-expert wave-parallel scan (8 waves == NEXP)
// -> tile table -> rowmap (compacted position -> original row; -1 = padding).
// No atomics.
__global__ __launch_bounds__(512)
void k_plan(const int* __restrict__ ids, int* __restrict__ ws,
            int* __restrict__ rowmap) {
    __shared__ int sc[512 * NEXP];   // per-thread per-expert counts -> prefixes
    __shared__ int seg[NEXP];
    __shared__ int tot[NEXP];
    int t = threadIdx.x;
    int myids[16];
    int base = t * 16;               // each thread owns 16 consecutive rows
#pragma unroll
    for (int e = 0; e < NEXP; e++) sc[t * NEXP + e] = 0;
#pragma unroll
    for (int i = 0; i < 16; i++) {
        myids[i] = ids[base + i];
        sc[t * NEXP + myids[i]]++;
    }
    __syncthreads();
    // wave w computes exclusive prefix over the 512 counts of expert w
    {
        int w = t >> 6, l = t & 63;
        int e = w;
        int vals[8], sum = 0;
#pragma unroll
        for (int j = 0; j < 8; j++) { vals[j] = sc[(l * 8 + j) * NEXP + e]; sum += vals[j]; }
        int inc = sum;
        for (int d = 1; d < 64; d <<= 1) {
            int v = __shfl_up(inc, d, 64);
            if (l >= d) inc += v;
        }
        int run = inc - sum;         // exclusive
#pragma unroll
        for (int j = 0; j < 8; j++) { int v = vals[j]; sc[(l * 8 + j) * NEXP + e] = run; run += v; }
        if (l == 63) tot[e] = run;
    }
    __syncthreads();
    if (t == 0) {
        int pos = 0, mt = 0;
        for (int e = 0; e < NEXP; e++) {
            int c = tot[e];
            seg[e] = pos;
            int ntl = (c + BM - 1) / BM;
            for (int tt = 0; tt < ntl; tt++) {
                ws[64  + mt] = e;
                ws[160 + mt] = pos + tt * BM;
                int v = c - tt * BM;
                ws[256 + mt] = v < BM ? v : BM;
                mt++;
            }
            pos += ntl * BM;
        }
        ws[48] = mt;
    }
    __syncthreads();
    for (int i = t; i < NROWS; i += 512) rowmap[i] = -1;
    __syncthreads();                 // init drained before fills
#pragma unroll
    for (int i = 0; i < 16; i++) {
        int e = myids[i];
        int p = seg[e] + sc[t * NEXP + e]++;
        rowmap[p] = base + i;
    }
}

// streaming prep, restructured for MLP: every thread issues ALL its global
// loads (4 x 16B = 64..128B in flight) BEFORE any convert/store, so the
// stream is never issue- or latency-serialized. 256-thread blocks, 8704
// blocks total (fine-grained TLP). Zero atomics, zero cross-block deps.
//   blocks [0, XHALF)        : 2 compacted rows each:
//                              xg[row] = bf16(x[rowmap[row]]) (zeros if -1)
//   blocks [XHALF, +WCVTB)   : W fp32 -> bf16, 4 chunks/thread, batched
__global__ __launch_bounds__(256)
void k_prep(const float* __restrict__ x, const int* __restrict__ rowmap,
            unsigned short* __restrict__ xg,
            const float4* __restrict__ W, uint4* __restrict__ Wb) {
    int b = blockIdx.x;
    int t = threadIdx.x;
    if (b < XHALF) {
        int r0 = b * 2, r1 = r0 + 1;
        int m0 = rowmap[r0], m1 = rowmap[r1];
        float4 L0 = {0,0,0,0}, L1 = {0,0,0,0}, L2 = {0,0,0,0}, L3 = {0,0,0,0};
        if (m0 >= 0) {
            const float4* s = (const float4*)(x + (size_t)m0 * DIM);
            L0 = s[2 * t]; L1 = s[2 * t + 1];
        }
        if (m1 >= 0) {
            const float4* s = (const float4*)(x + (size_t)m1 * DIM);
            L2 = s[2 * t]; L3 = s[2 * t + 1];
        }
        uint4 v0, v1;
        v0.x = f2bf2(L0.x, L0.y); v0.y = f2bf2(L0.z, L0.w);
        v0.z = f2bf2(L1.x, L1.y); v0.w = f2bf2(L1.z, L1.w);
        v1.x = f2bf2(L2.x, L2.y); v1.y = f2bf2(L2.z, L2.w);
        v1.z = f2bf2(L3.x, L3.y); v1.w = f2bf2(L3.z, L3.w);
        ((uint4*)(xg + (size_t)r0 * DIM))[t] = v0;
        ((uint4*)(xg + (size_t)r1 * DIM))[t] = v1;
        return;
    }
    size_t base = (size_t)(b - XHALF) * 1024;   // uint4 out-chunk index
    float4 L[8];
#pragma unroll
    for (int k = 0; k < 4; k++) {
        size_t o = base + (size_t)k * 256 + t;
        L[2 * k]     = W[o * 2];
        L[2 * k + 1] = W[o * 2 + 1];
    }
#pragma unroll
    for (int k = 0; k < 4; k++) {
        size_t o = base + (size_t)k * 256 + t;
        uint4 v;
        v.x = f2bf2(L[2 * k].x,     L[2 * k].y);
        v.y = f2bf2(L[2 * k].z,     L[2 * k].w);
        v.z = f2bf2(L[2 * k + 1].x, L[2 * k + 1].y);
        v.w = f2bf2(L[2 * k + 1].z, L[2 * k + 1].w);
        Wb[o] = v;
    }
}

// grouped GEMM — round-0/5 PROVEN version (134 us measured): 128x128 tile,
// 4 waves (2x2 of 64x64), BK=32, DOUBLE-BUFFERED LDS, single barrier per
// iter (drains vmcnt(0)); prefetch tile i+1 during compute of tile i.
// Both A and B staged via global_load_lds from CONTIGUOUS sources (xg is
// compacted). Swizzle: 16B chunk at LDS position p of row r holds logical
// chunk p ^ ((r>>1)&3) -> 2-way (free) bank aliasing on ds_read_b128,
// applied on the staging SOURCE address (dest stays wave-uniform linear).
// Grid dim3(16,72): XCD = nb%8 -> each 512KB B-panel owned by one XCD,
// L2-resident across that expert's m-tiles (proven mapping).
__launch_bounds__(256)
__global__ void k_gemm(const unsigned short* __restrict__ xg,
                       const unsigned short* __restrict__ Wb,
                       const float* __restrict__ bias,
                       const int* __restrict__ ws, const int* __restrict__ rowmap,
                       float* __restrict__ out) {
    int mt = blockIdx.y;
    if (mt >= ws[48]) return;
    int e     = ws[64  + mt];
    int pos0  = ws[160 + mt];
    int valid = ws[256 + mt];
    int n0 = blockIdx.x * BN;

    __shared__ unsigned short lds[2][8192];  // [buf][0..4095]=A, [4096..8191]=B; 32 KB

    int tid = threadIdx.x;
    int w = tid >> 6, l = tid & 63;
    int lane15 = l & 15, quad = l >> 4;
    int wave_m = (w >> 1) * 64, wave_n = (w & 1) * 64;

    const unsigned short* Abase = xg + (size_t)pos0 * DIM;
    const unsigned short* Bbase = Wb + (size_t)e * DIM * DIM + (size_t)n0 * DIM;

    // staging source offsets (shorts), invariant across K except +k0.
    // tile side = 512 chunks of 16B; wave w stages chunks [w*128, w*128+128)
    // in 2 issues of 64. chunk c: row=c>>2, dest pos=c&3, src q = pos^((row>>1)&3)
    int srcOff[2];
#pragma unroll
    for (int j = 0; j < 2; j++) {
        int c = w * 128 + j * 64 + l;
        int row = c >> 2, pos = c & 3;
        int q = pos ^ ((row >> 1) & 3);
        srcOff[j] = row * DIM + q * 8;
    }

    // fragment read offsets (shorts), loop-invariant.
    int swz = (quad ^ ((lane15 >> 1) & 3)) * 8;
    int afOff[4], bfOff[4];
#pragma unroll
    for (int mi = 0; mi < 4; mi++)
        afOff[mi] = (wave_m + mi * 16 + lane15) * BK + swz;
#pragma unroll
    for (int ni = 0; ni < 4; ni++)
        bfOff[ni] = 4096 + (wave_n + ni * 16 + lane15) * BK + swz;

    f32x4 acc[4][4];
#pragma unroll
    for (int i = 0; i < 4; i++)
#pragma unroll
        for (int j = 0; j < 4; j++) acc[i][j] = (f32x4){0.f, 0.f, 0.f, 0.f};

#define ISSUE(buf, k0)                                                          \
    do {                                                                        \
        _Pragma("unroll")                                                       \
        for (int j = 0; j < 2; j++) {                                           \
            __builtin_amdgcn_global_load_lds(                                   \
                AS1(Abase + (k0) + srcOff[j]),                                  \
                AS3(&lds[buf][w * 1024 + j * 512]), 16, 0, 0);                  \
            __builtin_amdgcn_global_load_lds(                                   \
                AS1(Bbase + (k0) + srcOff[j]),                                  \
                AS3(&lds[buf][4096 + w * 1024 + j * 512]), 16, 0, 0);           \
        }                                                                       \
    } while (0)

    ISSUE(0, 0);
    int cur = 0;
    for (int i = 0; i < NITER; ++i) {
        __syncthreads();   // drains vmcnt(0): loads(i) complete (in flight
                           // during compute(i-1)); all compute(i-1) done.
        if (i + 1 < NITER) {
            int k0n = (i + 1) * BK;
            ISSUE(cur ^ 1, k0n);
        }
        bf16x8 af[4], bf[4];
#pragma unroll
        for (int mi = 0; mi < 4; mi++)
            af[mi] = *(const bf16x8*)(&lds[cur][afOff[mi]]);
#pragma unroll
        for (int ni = 0; ni < 4; ni++)
            bf[ni] = *(const bf16x8*)(&lds[cur][bfOff[ni]]);
#pragma unroll
        for (int mi = 0; mi < 4; mi++)
#pragma unroll
            for (int ni = 0; ni < 4; ni++)
                acc[mi][ni] = __builtin_amdgcn_mfma_f32_16x16x32_bf16(
                    af[mi], bf[ni], acc[mi][ni], 0, 0, 0);
        cur ^= 1;
    }
#undef ISSUE

    // epilogue: bias + relu + residual(from xg, bf16, contiguous) + scatter
    float bv[4];
#pragma unroll
    for (int ni = 0; ni < 4; ni++)
        bv[ni] = bias[(size_t)e * DIM + n0 + wave_n + ni * 16 + lane15];
#pragma unroll
    for (int mi = 0; mi < 4; mi++) {
#pragma unroll
        for (int r4 = 0; r4 < 4; r4++) {
            int rl = wave_m + mi * 16 + quad * 4 + r4;
            if (rl < valid) {
                int orig = rowmap[pos0 + rl];
                const unsigned short* xrow = xg + (size_t)(pos0 + rl) * DIM + n0;
                float* orow = out + (size_t)orig * DIM + n0;
#pragma unroll
                for (int ni = 0; ni < 4; ni++) {
                    int col = wave_n + ni * 16 + lane15;
                    float xv = __uint_as_float((unsigned)xrow[col] << 16);
                    float v = acc[mi][ni][r4] + bv[ni];
                    v = v > 0.f ? v : 0.f;
                    orow[col] = xv + v;
                }
            }
        }
    }
}

// slow-but-correct fallback if workspace is too small
__global__ void k_naive(const float* __restrict__ x, const int* __restrict__ ids,
                        const float* __restrict__ W, const float* __restrict__ b,
                        float* __restrict__ out) {
    __shared__ float lx[DIM];
    int i = blockIdx.x;
    for (int t = threadIdx.x; t < DIM; t += blockDim.x) lx[t] = x[(size_t)i * DIM + t];
    __syncthreads();
    int e = ids[i];
    const float* We = W + (size_t)e * DIM * DIM;
    for (int n = threadIdx.x; n < DIM; n += blockDim.x) {
        const float* wr = We + (size_t)n * DIM;
        float acc = 0.f;
        for (int k = 0; k < DIM; k += 4) {
            float4 w4 = *(const float4*)(wr + k);
            acc += lx[k] * w4.x + lx[k + 1] * w4.y + lx[k + 2] * w4.z + lx[k + 3] * w4.w;
        }
        float v = acc + b[(size_t)e * DIM + n];
        v = v > 0.f ? v : 0.f;
        out[(size_t)i * DIM + n] = lx[n] + v;
    }
}

extern "C" void kernel_launch(void* const* d_in, const int* in_sizes, int n_in,
                              void* d_out, int out_size, void* d_ws, size_t ws_size,
                              hipStream_t stream) {
    const float* x   = (const float*)d_in[0];
    const int*   ids = (const int*)d_in[1];
    const float* W   = (const float*)d_in[2];
    const float* b   = (const float*)d_in[3];
    float* out = (float*)d_out;

    if (ws_size < WS_NEED) {
        k_naive<<<BATCH, 256, 0, stream>>>(x, ids, W, b, out);
        return;
    }

    char* wsb = (char*)d_ws;
    int*  wsi = (int*)wsb;
    int* rowmap = wsi + 512;
    unsigned short* xg = (unsigned short*)(wsb + XG_BYTE_OFF);
    unsigned short* Wb = (unsigned short*)(wsb + WB_BYTE_OFF);

    k_plan<<<1, 512, 0, stream>>>(ids, wsi, rowmap);
    k_prep<<<XHALF + WCVTB, 256, 0, stream>>>(x, rowmap, xg,
                                              (const float4*)W, (uint4*)Wb);
    dim3 g(NBLK, MAX_TILES);
    k_gemm<<<g, 256, 0, stream>>>(xg, Wb, b, wsi, rowmap, out);
}

// Round 8
// 389.691 us; speedup vs baseline: 1.0766x; 1.0150x over previous
//
#include <hip/hip_runtime.h>
#include <hip/hip_bf16.h>
#include <stdint.h>

#define BATCH 8192
#define DIM   2048
#define NEXP  8
#define BM    256
#define BN    128
#define BK    64
#define NKT   (DIM / BK)   // 32 K-tiles
#define MTILES 40          // max Σ ceil(c_e/256) = 32 + 7 guard
#define NBLK  (DIM / BN)   // 16
#define XHALF 4096         // x gather blocks: 8192 rows / 2 per block
#define WCVTB 4096         // W cvt blocks

typedef __bf16 bf16x8 __attribute__((ext_vector_type(8)));
typedef float  f32x4  __attribute__((ext_vector_type(4)));

// ---- workspace layout ----
// metadata ints 0..511 (ntiles@48 tileExp@64 tilePos0@160 tileVal@256)
// rowmap @ int 512 (8192 ints)
// xg (bf16, compacted, 8448 rows incl. 256-row read slack) @ byte 40960
// Wb (bf16) @ byte 37,789,696
#define XG_BYTE_OFF 40960ull
#define WB_BYTE_OFF 37789696ull
#define WS_NEED     104898560ull

#define AS1(p) ((const __attribute__((address_space(1))) void*)(p))
#define AS3(p) ((__attribute__((address_space(3))) void*)(p))

__device__ __forceinline__ unsigned f2bf2(float lo, float hi) {
    unsigned ul = __float_as_uint(lo), uh = __float_as_uint(hi);
    ul = (ul + 0x7FFFu + ((ul >> 16) & 1u)) >> 16;   // RNE
    uh = (uh + 0x7FFFu + ((uh >> 16) & 1u)) >> 16;
    return (uh << 16) | ul;
}

// single block: histogram -> per-expert wave-parallel scan -> 256-row tile
// table (contiguous segments, NO padding) -> rowmap. No atomics.
// Tail tiles intentionally over-read into the next segment / xg slack; those
// acc rows are >= valid and never stored.
__global__ __launch_bounds__(512)
void k_plan(const int* __restrict__ ids, int* __restrict__ ws,
            int* __restrict__ rowmap) {
    __shared__ int sc[512 * NEXP];
    __shared__ int seg[NEXP];
    __shared__ int tot[NEXP];
    int t = threadIdx.x;
    int myids[16];
    int base = t * 16;
#pragma unroll
    for (int e = 0; e < NEXP; e++) sc[t * NEXP + e] = 0;
#pragma unroll
    for (int i = 0; i < 16; i++) {
        myids[i] = ids[base + i];
        sc[t * NEXP + myids[i]]++;
    }
    __syncthreads();
    {
        int w = t >> 6, l = t & 63;
        int e = w;
        int vals[8], sum = 0;
#pragma unroll
        for (int j = 0; j < 8; j++) { vals[j] = sc[(l * 8 + j) * NEXP + e]; sum += vals[j]; }
        int inc = sum;
        for (int d = 1; d < 64; d <<= 1) {
            int v = __shfl_up(inc, d, 64);
            if (l >= d) inc += v;
        }
        int run = inc - sum;
#pragma unroll
        for (int j = 0; j < 8; j++) { int v = vals[j]; sc[(l * 8 + j) * NEXP + e] = run; run += v; }
        if (l == 63) tot[e] = run;
    }
    __syncthreads();
    if (t == 0) {
        int pos = 0, mt = 0;
        for (int e = 0; e < NEXP; e++) {
            int c = tot[e];
            seg[e] = pos;
            int ntl = (c + BM - 1) / BM;
            for (int tt = 0; tt < ntl; tt++) {
                ws[64  + mt] = e;
                ws[160 + mt] = pos + tt * BM;
                int v = c - tt * BM;
                ws[256 + mt] = v < BM ? v : BM;
                mt++;
            }
            pos += c;                      // contiguous, no padding
        }
        ws[48] = mt;
    }
    __syncthreads();
#pragma unroll
    for (int i = 0; i < 16; i++) {
        int e = myids[i];
        int p = seg[e] + sc[t * NEXP + e]++;
        rowmap[p] = base + i;              // every p in [0,8192) written once
    }
}

// streaming prep (MLP-batched, r7-proven structure; no padding rows):
//   blocks [0, XHALF)       : 2 compacted rows each: xg[row]=bf16(x[rowmap[row]])
//   blocks [XHALF, +WCVTB)  : W fp32 -> bf16, 4 chunks/thread, load-batched
__global__ __launch_bounds__(256)
void k_prep(const float* __restrict__ x, const int* __restrict__ rowmap,
            unsigned short* __restrict__ xg,
            const float4* __restrict__ W, uint4* __restrict__ Wb) {
    int b = blockIdx.x;
    int t = threadIdx.x;
    if (b < XHALF) {
        int r0 = b * 2, r1 = r0 + 1;
        int m0 = rowmap[r0], m1 = rowmap[r1];
        const float4* s0 = (const float4*)(x + (size_t)m0 * DIM);
        const float4* s1 = (const float4*)(x + (size_t)m1 * DIM);
        float4 L0 = s0[2 * t], L1 = s0[2 * t + 1];
        float4 L2 = s1[2 * t], L3 = s1[2 * t + 1];
        uint4 v0, v1;
        v0.x = f2bf2(L0.x, L0.y); v0.y = f2bf2(L0.z, L0.w);
        v0.z = f2bf2(L1.x, L1.y); v0.w = f2bf2(L1.z, L1.w);
        v1.x = f2bf2(L2.x, L2.y); v1.y = f2bf2(L2.z, L2.w);
        v1.z = f2bf2(L3.x, L3.y); v1.w = f2bf2(L3.z, L3.w);
        ((uint4*)(xg + (size_t)r0 * DIM))[t] = v0;
        ((uint4*)(xg + (size_t)r1 * DIM))[t] = v1;
        return;
    }
    size_t base = (size_t)(b - XHALF) * 1024;
    float4 L[8];
#pragma unroll
    for (int k = 0; k < 4; k++) {
        size_t o = base + (size_t)k * 256 + t;
        L[2 * k]     = W[o * 2];
        L[2 * k + 1] = W[o * 2 + 1];
    }
#pragma unroll
    for (int k = 0; k < 4; k++) {
        size_t o = base + (size_t)k * 256 + t;
        uint4 v;
        v.x = f2bf2(L[2 * k].x,     L[2 * k].y);
        v.y = f2bf2(L[2 * k].z,     L[2 * k].w);
        v.z = f2bf2(L[2 * k + 1].x, L[2 * k + 1].y);
        v.w = f2bf2(L[2 * k + 1].z, L[2 * k + 1].w);
        Wb[o] = v;
    }
}

// grouped GEMM, counted-vmcnt phase-split schedule (T2+T3+T4+T5 port):
// 256x128 tile, 8 waves (4M x 2N, per-wave 64x64), BK=64.
// LDS: ring of 3 K-tile buffers (A 32KB + B 16KB each = 144 KB), prefetch
// distance 2. Per K-tile: 6 gload_lds/thread (A:4,B:2) issued 3+3 in the two
// phases; vmcnt(6) once per K-tile -> next tile's loads NEVER drained at a
// barrier (T4). Phase = {8 ds_read_b128 | 3 gloads -> s_barrier ->
// lgkmcnt(0)+sched_barrier -> setprio(1) -> 16 MFMA -> setprio(0) -> s_barrier}.
// Swizzle: 16B chunk at LDS pos p of row r holds logical chunk p ^ (r&7)
// (staging source pre-swizzle + same involution on read) -> every 8
// consecutive lanes of a ds_read_b128 hit 8 distinct bank granules.
// Safety: barrier at end of iter kt-1 proves all waves' reads of buf[(kt-1)%3]
// are in registers -> staging(kt+2) into that buffer is race-free; vmcnt(6)
// at iter kt drains exactly staging(kt+1) (12 outstanding - 6 newest).
// NOTE: counted vmcnt assumes NO other vmem ops in the loop (no spills: VGPR
// budget ~140 of 256 at 2 waves/SIMD).
__global__ __launch_bounds__(512)
void k_gemm(const unsigned short* __restrict__ xg,
            const unsigned short* __restrict__ Wb,
            const float* __restrict__ bias,
            const int* __restrict__ ws, const int* __restrict__ rowmap,
            float* __restrict__ out) {
    int mt = blockIdx.y;
    if (mt >= ws[48]) return;
    int e     = ws[64  + mt];
    int pos0  = ws[160 + mt];
    int valid = ws[256 + mt];
    int n0 = blockIdx.x * BN;

    __shared__ __align__(16) unsigned char lds[3 * 49152];  // 144 KB

    int tid = threadIdx.x;
    int w = tid >> 6, l = tid & 63;
    int l15 = l & 15, quad = l >> 4, x7 = l15 & 7;
    int wm = (w >> 1) * 64, wn = (w & 1) * 64;

    const unsigned short* Abase = xg + (size_t)pos0 * DIM;
    const unsigned short* Bbase = Wb + ((size_t)e * DIM + n0) * DIM;

    // staging: A = 2048 granules (256 rows x 8), wave w covers [w*256,+256)
    // in 4 instrs; B = 1024 granules (128 rows x 8), wave w covers [w*128,+128)
    // in 2 instrs. src granule (row,pos) <- logical chunk pos^(row&7).
    int srcA[4], srcB[2];
#pragma unroll
    for (int j = 0; j < 4; j++) {
        int g = w * 256 + j * 64 + l;
        int row = g >> 3, pos = g & 7;
        srcA[j] = row * DIM + (pos ^ (row & 7)) * 8;   // shorts
    }
#pragma unroll
    for (int j = 0; j < 2; j++) {
        int h = w * 128 + j * 64 + l;
        int row = h >> 3, pos = h & 7;
        srcB[j] = row * DIM + (pos ^ (row & 7)) * 8;
    }
    int dA0 = (w * 256) * 16;          // byte offsets within a buffer
    int dB0 = 32768 + (w * 128) * 16;

    // fragment read offsets (bytes within buffer), phys = (s*4+quad)^(l15&7)
    int aOff[2][4], bOff[2][4];
#pragma unroll
    for (int s = 0; s < 2; s++) {
        int ph = ((s * 4 + quad) ^ x7) * 16;
#pragma unroll
        for (int i = 0; i < 4; i++) {
            aOff[s][i] = (wm + i * 16 + l15) * 128 + ph;
            bOff[s][i] = 32768 + (wn + i * 16 + l15) * 128 + ph;
        }
    }

    f32x4 acc[4][4];
#pragma unroll
    for (int i = 0; i < 4; i++)
#pragma unroll
        for (int j = 0; j < 4; j++) acc[i][j] = (f32x4){0.f, 0.f, 0.f, 0.f};

#define GL(srcp, dstoff)                                                        \
    __builtin_amdgcn_global_load_lds(AS1(srcp), AS3(lds + (dstoff)), 16, 0, 0)
#define STAGE_P0(bb, k0)                                                        \
    do {                                                                        \
        GL(Abase + (k0) + srcA[0], (bb) + dA0);                                 \
        GL(Abase + (k0) + srcA[1], (bb) + dA0 + 1024);                          \
        GL(Bbase + (k0) + srcB[0], (bb) + dB0);                                 \
    } while (0)
#define STAGE_P1(bb, k0)                                                        \
    do {                                                                        \
        GL(Abase + (k0) + srcA[2], (bb) + dA0 + 2048);                          \
        GL(Abase + (k0) + srcA[3], (bb) + dA0 + 3072);                          \
        GL(Bbase + (k0) + srcB[1], (bb) + dB0 + 1024);                          \
    } while (0)

    // prologue: stage K-tiles 0,1; drain tile0, keep tile1 in flight
    STAGE_P0(0, 0);        STAGE_P1(0, 0);
    STAGE_P0(49152, BK);   STAGE_P1(49152, BK);
    asm volatile("s_waitcnt vmcnt(6)" ::: "memory");
    __builtin_amdgcn_s_barrier();

    int cur = 0;
    for (int kt = 0; kt < NKT; ++kt) {
        const unsigned char* pb = lds + cur * 49152;
        int pre = cur + 2; if (pre >= 3) pre -= 3;
        int preb = pre * 49152;
        int k2 = (kt + 2) * BK;
        bool dopre = (kt + 2 < NKT);
        // ---------------- phase 0 (k-slot s=0) ----------------
        {
            bf16x8 af[4], bf[4];
#pragma unroll
            for (int i = 0; i < 4; i++) af[i] = *(const bf16x8*)(pb + aOff[0][i]);
#pragma unroll
            for (int i = 0; i < 4; i++) bf[i] = *(const bf16x8*)(pb + bOff[0][i]);
            if (dopre) STAGE_P0(preb, k2);
            __builtin_amdgcn_s_barrier();
            asm volatile("s_waitcnt lgkmcnt(0)" ::: "memory");
            __builtin_amdgcn_sched_barrier(0);
            __builtin_amdgcn_s_setprio(1);
#pragma unroll
            for (int mi = 0; mi < 4; mi++)
#pragma unroll
                for (int ni = 0; ni < 4; ni++)
                    acc[mi][ni] = __builtin_amdgcn_mfma_f32_16x16x32_bf16(
                        af[mi], bf[ni], acc[mi][ni], 0, 0, 0);
            __builtin_amdgcn_s_setprio(0);
            __builtin_amdgcn_s_barrier();
        }
        // ---------------- phase 1 (k-slot s=1) ----------------
        {
            bf16x8 af[4], bf[4];
#pragma unroll
            for (int i = 0; i < 4; i++) af[i] = *(const bf16x8*)(pb + aOff[1][i]);
#pragma unroll
            for (int i = 0; i < 4; i++) bf[i] = *(const bf16x8*)(pb + bOff[1][i]);
            if (dopre) STAGE_P1(preb, k2);
            if (kt < NKT - 2) asm volatile("s_waitcnt vmcnt(6)" ::: "memory");
            else              asm volatile("s_waitcnt vmcnt(0)" ::: "memory");
            __builtin_amdgcn_sched_barrier(0);
            __builtin_amdgcn_s_barrier();
            asm volatile("s_waitcnt lgkmcnt(0)" ::: "memory");
            __builtin_amdgcn_sched_barrier(0);
            __builtin_amdgcn_s_setprio(1);
#pragma unroll
            for (int mi = 0; mi < 4; mi++)
#pragma unroll
                for (int ni = 0; ni < 4; ni++)
                    acc[mi][ni] = __builtin_amdgcn_mfma_f32_16x16x32_bf16(
                        af[mi], bf[ni], acc[mi][ni], 0, 0, 0);
            __builtin_amdgcn_s_setprio(0);
            __builtin_amdgcn_s_barrier();
        }
        cur += 1; if (cur == 3) cur = 0;
    }
#undef GL
#undef STAGE_P0
#undef STAGE_P1

    // epilogue: bias + relu + residual(from xg, bf16) + scatter
    float bv[4];
#pragma unroll
    for (int ni = 0; ni < 4; ni++)
        bv[ni] = bias[(size_t)e * DIM + n0 + wn + ni * 16 + l15];
#pragma unroll
    for (int mi = 0; mi < 4; mi++) {
#pragma unroll
        for (int r4 = 0; r4 < 4; r4++) {
            int rl = wm + mi * 16 + quad * 4 + r4;
            if (rl < valid) {
                int orig = rowmap[pos0 + rl];
                const unsigned short* xrow = xg + (size_t)(pos0 + rl) * DIM + n0;
                float* orow = out + (size_t)orig * DIM + n0;
#pragma unroll
                for (int ni = 0; ni < 4; ni++) {
                    int col = wn + ni * 16 + l15;
                    float xv = __uint_as_float((unsigned)xrow[col] << 16);
                    float v = acc[mi][ni][r4] + bv[ni];
                    v = v > 0.f ? v : 0.f;
                    orow[col] = xv + v;
                }
            }
        }
    }
}

// slow-but-correct fallback if workspace is too small
__global__ void k_naive(const float* __restrict__ x, const int* __restrict__ ids,
                        const float* __restrict__ W, const float* __restrict__ b,
                        float* __restrict__ out) {
    __shared__ float lx[DIM];
    int i = blockIdx.x;
    for (int t = threadIdx.x; t < DIM; t += blockDim.x) lx[t] = x[(size_t)i * DIM + t];
    __syncthreads();
    int e = ids[i];
    const float* We = W + (size_t)e * DIM * DIM;
    for (int n = threadIdx.x; n < DIM; n += blockDim.x) {
        const float* wr = We + (size_t)n * DIM;
        float acc = 0.f;
        for (int k = 0; k < DIM; k += 4) {
            float4 w4 = *(const float4*)(wr + k);
            acc += lx[k] * w4.x + lx[k + 1] * w4.y + lx[k + 2] * w4.z + lx[k + 3] * w4.w;
        }
        float v = acc + b[(size_t)e * DIM + n];
        v = v > 0.f ? v : 0.f;
        out[(size_t)i * DIM + n] = lx[n] + v;
    }
}

extern "C" void kernel_launch(void* const* d_in, const int* in_sizes, int n_in,
                              void* d_out, int out_size, void* d_ws, size_t ws_size,
                              hipStream_t stream) {
    const float* x   = (const float*)d_in[0];
    const int*   ids = (const int*)d_in[1];
    const float* W   = (const float*)d_in[2];
    const float* b   = (const float*)d_in[3];
    float* out = (float*)d_out;

    if (ws_size < WS_NEED) {
        k_naive<<<BATCH, 256, 0, stream>>>(x, ids, W, b, out);
        return;
    }

    char* wsb = (char*)d_ws;
    int*  wsi = (int*)wsb;
    int* rowmap = wsi + 512;
    unsigned short* xg = (unsigned short*)(wsb + XG_BYTE_OFF);
    unsigned short* Wb = (unsigned short*)(wsb + WB_BYTE_OFF);

    k_plan<<<1, 512, 0, stream>>>(ids, wsi, rowmap);
    k_prep<<<XHALF + WCVTB, 256, 0, stream>>>(x, rowmap, xg,
                                              (const float4*)W, (uint4*)Wb);
    dim3 g(NBLK, MTILES);
    k_gemm<<<g, 512, 0, stream>>>(xg, Wb, b, wsi, rowmap, out);
}